// Round 15
// baseline (172.220 us; speedup 1.0000x reference)
//
#include <hip/hip_runtime.h>

#define HH 128
#define WW 128
#define CCH 128
#define NKD 21
#define RAD 10
#define HPAD 148                 // tgt images per b (hp = h+dy, 0..147)
#define ROWH 32                  // halves per row (32c) = 64B — no pad needed (no LDS staging)
#define CH_HALVES (148 * ROWH)   // 4736 halves per chunk (148 p-rows)
#define CH_BYTES  (CH_HALVES * 2)        // 9472 B
#define IMG_HALVES (4 * CH_HALVES)       // 18944 halves per (b,hp) = 37888 B

typedef _Float16 f16x8 __attribute__((ext_vector_type(8)));
typedef float    f32x4 __attribute__((ext_vector_type(4)));
typedef __fp16   h2f   __attribute__((ext_vector_type(2)));

union PK { uint4 u; h2f h[4]; };

// ------- kernel 1: pack tgt -> f16 image [hp][chunk(32c)][p(148)][32 halves], zero-padded -------
__global__ __launch_bounds__(256)
void pack_tgt(const float* __restrict__ in, __fp16* __restrict__ img) {
    int n = blockIdx.x;                 // 592: b*148 + i (tgt row = i-10)
    int b = n / HPAD, i = n - b * HPAD;
    int tid = threadIdx.x;
    uint4* gi = (uint4*)(img + (size_t)n * IMG_HALVES);   // 2368 uint4 per image
    if (i < RAD || i > 137) {           // h out of range -> all-zero image
        uint4 z = make_uint4(0, 0, 0, 0);
#pragma unroll
        for (int k = 0; k < 9; ++k) gi[k * 256 + tid] = z;
        if (tid < 64) gi[9 * 256 + tid] = z;
        return;
    }
    __shared__ __align__(16) char sraw[4 * CH_BYTES];   // 37888 B
    {   // zero-fill (covers p<10, p>137 pad rows)
        uint4 z = make_uint4(0, 0, 0, 0);
        uint4* sp = (uint4*)sraw;
#pragma unroll
        for (int k = 0; k < 9; ++k) sp[k * 256 + tid] = z;
        if (tid < 64) sp[9 * 256 + tid] = z;
    }
    __syncthreads();
    const float* tg = in + (size_t)(b * 2 + 1) * CCH * HH * WW + (size_t)(i - RAD) * WW;
    int w = tid & 127, half = tid >> 7;
    int p = w + RAD;                    // 10..137
#pragma unroll
    for (int c2 = 0; c2 < 2; ++c2) {
        int cc = half * 2 + c2;         // chunk 0..3 (32 channels each)
#pragma unroll
        for (int g = 0; g < 4; ++g) {   // slot g = halves c_local g*8..g*8+7
            float v[8];
#pragma unroll
            for (int j = 0; j < 8; ++j)
                v[j] = tg[(size_t)(cc * 32 + g * 8 + j) * (HH * WW) + w];
            PK q;
            q.h[0] = __builtin_amdgcn_cvt_pkrtz(v[0], v[1]);
            q.h[1] = __builtin_amdgcn_cvt_pkrtz(v[2], v[3]);
            q.h[2] = __builtin_amdgcn_cvt_pkrtz(v[4], v[5]);
            q.h[3] = __builtin_amdgcn_cvt_pkrtz(v[6], v[7]);
            *(uint4*)(sraw + (size_t)cc * CH_BYTES + p * 64 + g * 16) = q.u;
        }
    }
    __syncthreads();
    const uint4* si = (const uint4*)sraw;
#pragma unroll
    for (int k = 0; k < 9; ++k) gi[k * 256 + tid] = si[k * 256 + tid];
    if (tid < 64) gi[9 * 256 + tid] = si[9 * 256 + tid];
}

// -------- kernel 2: 2-row block, dy-split-4 (grid 1024 -> 4 blocks/CU), barrier-free --------
// Block d covers ph_g in [start_d, start_d+cnt_d): d0:0-5 d1:6-11 d2:12-16 d3:17-21.
// row0 (h0) dy=ph_g (if <=20); row1 (h0+1) dy=ph_g-1 (if >=1). Partitions exact/disjoint.
// B-fragments read directly from packed global image (L2/L3-resident), 2-deep reg ring.
// MFMA: a (w-rows) FIRST, bfr (p-cols) SECOND -> acc rows=w(4g+j), cols=p(r).
__global__ __launch_bounds__(256, 4)
void corr_mfma(const float* __restrict__ in, const __fp16* __restrict__ img_tgt,
               float* __restrict__ out) {
    int n = blockIdx.x;                 // 1024
    int xcd = n & 7, idx = n >> 3;
    int u = xcd * 128 + idx;            // 4 d-blocks of a pair adjacent on one XCD
    int d = u & 3;                      // dy-split quarter
    int hpair = u >> 2;                 // 0..255
    int b = hpair >> 6;                 // 0..3
    int h0 = (hpair & 63) << 1;         // even row base

    const int start_d = (d < 2) ? d * 6 : 12 + (d - 2) * 5;
    const int cnt_d   = (d < 2) ? 6 : 5;

    // LDS: s_srch (16KB, prologue) overlaid by s_o (25.6KB, wave-private slabs)
    __shared__ __align__(16) char smem[25600];
    __fp16* s_srch = (__fp16*)smem;
    float*  s_o    = (float*)smem;

    int tid = threadIdx.x;
    int q = tid >> 6, lane = tid & 63, r = lane & 15, g = lane >> 4;

    const char* tgbc = (const char*)(img_tgt + (size_t)(b * HPAD) * IMG_HALVES);
    const int hbase = h0 + start_d;     // hp = hbase + (t>>2), max 126+17+4 = 147

    // ---- pack src rows via 16KB c-half buffer; A-frags to regs ----
    f16x8 a[2][2][4];   // [row][wi][cc-group]
#pragma unroll
    for (int row = 0; row < 2; ++row) {
        const float* src = in + (size_t)(b * 2) * CCH * HH * WW + (size_t)(h0 + row) * WW;
        const float sc = 1.f / 128.f;
        int w = tid & 127, hb = tid >> 7;
#pragma unroll
        for (int chalf = 0; chalf < 2; ++chalf) {
#pragma unroll
            for (int i4 = 0; i4 < 4; ++i4) {
                int t4 = hb * 4 + i4;           // c-block within half, 0..7
                float v[8];
#pragma unroll
                for (int j = 0; j < 8; ++j)
                    v[j] = src[(size_t)(chalf * 64 + t4 * 8 + j) * (HH * WW) + w] * sc;
                PK qq;
                qq.h[0] = __builtin_amdgcn_cvt_pkrtz(v[0], v[1]);
                qq.h[1] = __builtin_amdgcn_cvt_pkrtz(v[2], v[3]);
                qq.h[2] = __builtin_amdgcn_cvt_pkrtz(v[4], v[5]);
                qq.h[3] = __builtin_amdgcn_cvt_pkrtz(v[6], v[7]);
                int slot = t4 ^ (w & 7);
                *(uint4*)&s_srch[w * 64 + slot * 8] = qq.u;
            }
            __syncthreads();
#pragma unroll
            for (int wi = 0; wi < 2; ++wi) {
                int wrow = (2 * q + wi) * 16 + r;
#pragma unroll
                for (int ksl = 0; ksl < 2; ++ksl) {
                    int slot = (ksl * 4 + g) ^ (wrow & 7);
                    a[row][wi][chalf * 2 + ksl] = *(const f16x8*)&s_srch[wrow * 64 + slot * 8];
                }
            }
            asm volatile("s_waitcnt lgkmcnt(0)" ::: "memory");
            __syncthreads();   // frags in regs everywhere before re-pack / s_o overlay
        }
    }

    // ---- static per-thread byte offsets within a chunk (clamped band rows) ----
    // prow>147 clamped to 147: feeds only acc columns p>=148, never stored.
    int off[4];
#pragma unroll
    for (int pi = 0; pi < 4; ++pi) {
        int prow = (2 * q + pi) * 16 + r;
        if (prow > 147) prow = 147;
        off[pi] = prow * 64 + g * 16;
    }

    float* outb = out + (size_t)b * (NKD * NKD) * (HH * WW) + (size_t)h0 * WW;
    float* so = s_o + q * (32 * 50);

    const int tmax = cnt_d * 4;

    // 2-deep register prefetch ring over the block's chunks; chunk t in buf[t&1].
    uint4 buf[2][4];
    {
        const char* c0 = tgbc + ((size_t)hbase * 4 + 0) * CH_BYTES;
        const char* c1 = tgbc + ((size_t)hbase * 4 + 1) * CH_BYTES;
#pragma unroll
        for (int pi = 0; pi < 4; ++pi) buf[0][pi] = *(const uint4*)(c0 + off[pi]);
#pragma unroll
        for (int pi = 0; pi < 4; ++pi) buf[1][pi] = *(const uint4*)(c1 + off[pi]);
    }

    for (int phl = 0; phl < cnt_d; ++phl) {
        int ph_g = start_d + phl;
        int row0_on = (ph_g <= 20);
        int row1_on = (ph_g >= 1);

        f32x4 acc[2][2][3];   // [row][wi][pj]
#pragma unroll
        for (int row = 0; row < 2; ++row)
#pragma unroll
            for (int wi = 0; wi < 2; ++wi)
#pragma unroll
                for (int pj = 0; pj < 3; ++pj)
#pragma unroll
                    for (int j = 0; j < 4; ++j) acc[row][wi][pj][j] = 0.f;

#pragma unroll
        for (int cc = 0; cc < 4; ++cc) {
            int t = phl * 4 + cc;
            f16x8 bfr[4];
#pragma unroll
            for (int pi = 0; pi < 4; ++pi)
                bfr[pi] = __builtin_bit_cast(f16x8, buf[cc & 1][pi]);

            if (t + 2 < tmax) {   // prefetch chunk t+2 into the slot just consumed
                const char* cp = tgbc
                    + ((size_t)(hbase + ((t + 2) >> 2)) * 4 + ((t + 2) & 3)) * CH_BYTES;
#pragma unroll
                for (int pi = 0; pi < 4; ++pi)
                    buf[cc & 1][pi] = *(const uint4*)(cp + off[pi]);
            }

            if (row0_on) {
#pragma unroll
                for (int wi = 0; wi < 2; ++wi)
#pragma unroll
                    for (int pj = 0; pj < 3; ++pj)
                        acc[0][wi][pj] = __builtin_amdgcn_mfma_f32_16x16x32_f16(
                            a[0][wi][cc], bfr[wi + pj], acc[0][wi][pj], 0, 0, 0);
            }
            if (row1_on) {
#pragma unroll
                for (int wi = 0; wi < 2; ++wi)
#pragma unroll
                    for (int pj = 0; pj < 3; ++pj)
                        acc[1][wi][pj] = __builtin_amdgcn_mfma_f32_16x16x32_f16(
                            a[1][wi][cc], bfr[wi + pj], acc[1][wi][pj], 0, 0, 0);
            }
        }

        // ---- staggered epilogues: row0 dy=ph_g, row1 dy=ph_g-1 (s_o wave-private) ----
#pragma unroll
        for (int row = 0; row < 2; ++row) {
            int dy = ph_g - row;
            if ((row == 0 && !row0_on) || (row == 1 && !row1_on)) continue;
#pragma unroll
            for (int wi = 0; wi < 2; ++wi)
#pragma unroll
                for (int pj = 0; pj < 3; ++pj)
#pragma unroll
                    for (int j = 0; j < 4; ++j)
                        so[(wi * 16 + 4 * g + j) * 50 + pj * 16 + r] = acc[row][wi][pj][j];
            asm volatile("s_waitcnt lgkmcnt(0)" ::: "memory");
            __builtin_amdgcn_sched_barrier(0);
            float* op = outb + (size_t)row * WW + (size_t)dy * NKD * (HH * WW);
#pragma unroll
            for (int k = 0; k < 3; ++k) {
                int f = k * 64 + lane;
                if (f < NKD * 8) {
                    int dx = f >> 3, w4l = (f & 7) << 2;   // local w in wave's 32-w slab
                    float4 v;
                    v.x = so[(w4l + 0) * 50 + ((w4l + 0) & 15) + dx];
                    v.y = so[(w4l + 1) * 50 + ((w4l + 1) & 15) + dx];
                    v.z = so[(w4l + 2) * 50 + ((w4l + 2) & 15) + dx];
                    v.w = so[(w4l + 3) * 50 + ((w4l + 3) & 15) + dx];
                    *(float4*)&op[(size_t)dx * (HH * WW) + q * 32 + w4l] = v;
                }
            }
            asm volatile("s_waitcnt lgkmcnt(0)" ::: "memory");  // reads done before row1 rewrites
        }
    }
}

extern "C" void kernel_launch(void* const* d_in, const int* in_sizes, int n_in,
                              void* d_out, int out_size, void* d_ws, size_t ws_size,
                              hipStream_t stream) {
    const float* in = (const float*)d_in[0];
    float* out = (float*)d_out;
    __fp16* img_tgt = (__fp16*)d_ws;

    hipLaunchKernelGGL(pack_tgt, dim3(4 * HPAD), dim3(256), 0, stream, in, img_tgt);
    hipLaunchKernelGGL(corr_mfma, dim3(1024), dim3(256), 0, stream, in, img_tgt, out);
}

// Round 16
// 86.770 us; speedup vs baseline: 1.9848x; 1.9848x over previous
//
#include <hip/hip_runtime.h>

#define HH 128
#define WW 128
#define CCH 128
#define NKD 21
#define RAD 10
#define HPAD 148                 // tgt images per b (hp = h+dy, 0..147)
#define ROWH 32                  // halves per row (32c) = 64B
#define CH_HALVES (148 * ROWH)   // 4736 halves per chunk (148 p-rows)
#define CH_BYTES  (CH_HALVES * 2)        // 9472 B
#define IMG_HALVES (4 * CH_HALVES)       // 18944 halves per (b,hp) = 37888 B

typedef _Float16 f16x8 __attribute__((ext_vector_type(8)));
typedef float    f32x4 __attribute__((ext_vector_type(4)));
typedef __fp16   h2f   __attribute__((ext_vector_type(2)));

union PK { uint4 u; h2f h[4]; };

// ------- kernel 1: pack tgt -> f16 image [hp][chunk(32c)][p(148)][32 halves], zero-padded -------
__global__ __launch_bounds__(256)
void pack_tgt(const float* __restrict__ in, __fp16* __restrict__ img) {
    int n = blockIdx.x;                 // 592: b*148 + i (tgt row = i-10)
    int b = n / HPAD, i = n - b * HPAD;
    int tid = threadIdx.x;
    uint4* gi = (uint4*)(img + (size_t)n * IMG_HALVES);   // 2368 uint4 per image
    if (i < RAD || i > 137) {           // h out of range -> all-zero image
        uint4 z = make_uint4(0, 0, 0, 0);
#pragma unroll
        for (int k = 0; k < 9; ++k) gi[k * 256 + tid] = z;
        if (tid < 64) gi[9 * 256 + tid] = z;
        return;
    }
    __shared__ __align__(16) char sraw[4 * CH_BYTES];   // 37888 B
    {   // zero-fill (covers p<10, p>137 pad rows)
        uint4 z = make_uint4(0, 0, 0, 0);
        uint4* sp = (uint4*)sraw;
#pragma unroll
        for (int k = 0; k < 9; ++k) sp[k * 256 + tid] = z;
        if (tid < 64) sp[9 * 256 + tid] = z;
    }
    __syncthreads();
    const float* tg = in + (size_t)(b * 2 + 1) * CCH * HH * WW + (size_t)(i - RAD) * WW;
    int w = tid & 127, half = tid >> 7;
    int p = w + RAD;                    // 10..137
#pragma unroll
    for (int c2 = 0; c2 < 2; ++c2) {
        int cc = half * 2 + c2;         // chunk 0..3 (32 channels each)
#pragma unroll
        for (int g = 0; g < 4; ++g) {   // slot g = halves c_local g*8..g*8+7
            float v[8];
#pragma unroll
            for (int j = 0; j < 8; ++j)
                v[j] = tg[(size_t)(cc * 32 + g * 8 + j) * (HH * WW) + w];
            PK q;
            q.h[0] = __builtin_amdgcn_cvt_pkrtz(v[0], v[1]);
            q.h[1] = __builtin_amdgcn_cvt_pkrtz(v[2], v[3]);
            q.h[2] = __builtin_amdgcn_cvt_pkrtz(v[4], v[5]);
            q.h[3] = __builtin_amdgcn_cvt_pkrtz(v[6], v[7]);
            *(uint4*)(sraw + (size_t)cc * CH_BYTES + p * 64 + g * 16) = q.u;
        }
    }
    __syncthreads();
    const uint4* si = (const uint4*)sraw;
#pragma unroll
    for (int k = 0; k < 9; ++k) gi[k * 256 + tid] = si[k * 256 + tid];
    if (tid < 64) gi[9 * 256 + tid] = si[9 * 256 + tid];
}

// -------- kernel 2: 2-row block, dy-split-3 (grid 768 -> 3 blocks/CU), barrier-free --------
// Block d covers ph_g in [start_d, start_d+cnt_d): d0:0-7 d1:8-14 d2:15-21.
// row0 (h0) dy=ph_g (if <=20); row1 (h0+1) dy=ph_g-1 (if >=1). Partitions exact/disjoint.
// Register budget: launch_bounds(256,3) -> 170-reg unified cap >= ~160 live (no spill).
// B-fragments read directly from packed global image (L2/L3-resident), 2-deep reg ring.
// MFMA: a (w-rows) FIRST, bfr (p-cols) SECOND -> acc rows=w(4g+j), cols=p(r).
__global__ __launch_bounds__(256, 3)
void corr_mfma(const float* __restrict__ in, const __fp16* __restrict__ img_tgt,
               float* __restrict__ out) {
    int n = blockIdx.x;                 // 768
    int xcd = n & 7, idx = n >> 3;      // idx 0..95
    int u = xcd * 96 + idx;             // 3 d-blocks of a pair adjacent on one XCD
    int d = u % 3;                      // dy-split third
    int hpair = u / 3;                  // 0..255
    int b = hpair >> 6;                 // 0..3
    int h0 = (hpair & 63) << 1;         // even row base

    const int start_d = (d == 0) ? 0 : (d == 1 ? 8 : 15);
    const int cnt_d   = (d == 0) ? 8 : 7;

    // LDS: s_srch (16KB, prologue) overlaid by s_o (25.6KB, wave-private slabs)
    __shared__ __align__(16) char smem[25600];
    __fp16* s_srch = (__fp16*)smem;
    float*  s_o    = (float*)smem;

    int tid = threadIdx.x;
    int q = tid >> 6, lane = tid & 63, r = lane & 15, g = lane >> 4;

    const char* tgbc = (const char*)(img_tgt + (size_t)(b * HPAD) * IMG_HALVES);
    const int hbase = h0 + start_d;     // hp = hbase + (t>>2), max 126+15+6 = 147

    // ---- pack src rows via 16KB c-half buffer; A-frags to regs ----
    f16x8 a[2][2][4];   // [row][wi][cc-group]
#pragma unroll
    for (int row = 0; row < 2; ++row) {
        const float* src = in + (size_t)(b * 2) * CCH * HH * WW + (size_t)(h0 + row) * WW;
        const float sc = 1.f / 128.f;
        int w = tid & 127, hb = tid >> 7;
#pragma unroll
        for (int chalf = 0; chalf < 2; ++chalf) {
#pragma unroll
            for (int i4 = 0; i4 < 4; ++i4) {
                int t4 = hb * 4 + i4;           // c-block within half, 0..7
                float v[8];
#pragma unroll
                for (int j = 0; j < 8; ++j)
                    v[j] = src[(size_t)(chalf * 64 + t4 * 8 + j) * (HH * WW) + w] * sc;
                PK qq;
                qq.h[0] = __builtin_amdgcn_cvt_pkrtz(v[0], v[1]);
                qq.h[1] = __builtin_amdgcn_cvt_pkrtz(v[2], v[3]);
                qq.h[2] = __builtin_amdgcn_cvt_pkrtz(v[4], v[5]);
                qq.h[3] = __builtin_amdgcn_cvt_pkrtz(v[6], v[7]);
                int slot = t4 ^ (w & 7);
                *(uint4*)&s_srch[w * 64 + slot * 8] = qq.u;
            }
            __syncthreads();
#pragma unroll
            for (int wi = 0; wi < 2; ++wi) {
                int wrow = (2 * q + wi) * 16 + r;
#pragma unroll
                for (int ksl = 0; ksl < 2; ++ksl) {
                    int slot = (ksl * 4 + g) ^ (wrow & 7);
                    a[row][wi][chalf * 2 + ksl] = *(const f16x8*)&s_srch[wrow * 64 + slot * 8];
                }
            }
            asm volatile("s_waitcnt lgkmcnt(0)" ::: "memory");
            __syncthreads();   // frags in regs everywhere before re-pack / s_o overlay
        }
    }

    // ---- static per-thread byte offsets within a chunk (clamped band rows) ----
    // prow>147 clamped to 147: feeds only acc columns p>=148, never stored.
    int off[4];
#pragma unroll
    for (int pi = 0; pi < 4; ++pi) {
        int prow = (2 * q + pi) * 16 + r;
        if (prow > 147) prow = 147;
        off[pi] = prow * 64 + g * 16;
    }

    float* outb = out + (size_t)b * (NKD * NKD) * (HH * WW) + (size_t)h0 * WW;
    float* so = s_o + q * (32 * 50);

    const int tmax = cnt_d * 4;

    // 2-deep register prefetch ring over the block's chunks; chunk t in buf[t&1].
    uint4 buf[2][4];
    {
        const char* c0 = tgbc + ((size_t)hbase * 4 + 0) * CH_BYTES;
        const char* c1 = tgbc + ((size_t)hbase * 4 + 1) * CH_BYTES;
#pragma unroll
        for (int pi = 0; pi < 4; ++pi) buf[0][pi] = *(const uint4*)(c0 + off[pi]);
#pragma unroll
        for (int pi = 0; pi < 4; ++pi) buf[1][pi] = *(const uint4*)(c1 + off[pi]);
    }

    for (int phl = 0; phl < cnt_d; ++phl) {
        int ph_g = start_d + phl;
        int row0_on = (ph_g <= 20);
        int row1_on = (ph_g >= 1);

        f32x4 acc[2][2][3];   // [row][wi][pj]
#pragma unroll
        for (int row = 0; row < 2; ++row)
#pragma unroll
            for (int wi = 0; wi < 2; ++wi)
#pragma unroll
                for (int pj = 0; pj < 3; ++pj)
#pragma unroll
                    for (int j = 0; j < 4; ++j) acc[row][wi][pj][j] = 0.f;

#pragma unroll
        for (int cc = 0; cc < 4; ++cc) {
            int t = phl * 4 + cc;
            f16x8 bfr[4];
#pragma unroll
            for (int pi = 0; pi < 4; ++pi)
                bfr[pi] = __builtin_bit_cast(f16x8, buf[cc & 1][pi]);

            if (t + 2 < tmax) {   // prefetch chunk t+2 into the slot just consumed
                const char* cp = tgbc
                    + ((size_t)(hbase + ((t + 2) >> 2)) * 4 + ((t + 2) & 3)) * CH_BYTES;
#pragma unroll
                for (int pi = 0; pi < 4; ++pi)
                    buf[cc & 1][pi] = *(const uint4*)(cp + off[pi]);
            }

            if (row0_on) {
#pragma unroll
                for (int wi = 0; wi < 2; ++wi)
#pragma unroll
                    for (int pj = 0; pj < 3; ++pj)
                        acc[0][wi][pj] = __builtin_amdgcn_mfma_f32_16x16x32_f16(
                            a[0][wi][cc], bfr[wi + pj], acc[0][wi][pj], 0, 0, 0);
            }
            if (row1_on) {
#pragma unroll
                for (int wi = 0; wi < 2; ++wi)
#pragma unroll
                    for (int pj = 0; pj < 3; ++pj)
                        acc[1][wi][pj] = __builtin_amdgcn_mfma_f32_16x16x32_f16(
                            a[1][wi][cc], bfr[wi + pj], acc[1][wi][pj], 0, 0, 0);
            }
        }

        // ---- staggered epilogues: row0 dy=ph_g, row1 dy=ph_g-1 (s_o wave-private) ----
#pragma unroll
        for (int row = 0; row < 2; ++row) {
            int dy = ph_g - row;
            if ((row == 0 && !row0_on) || (row == 1 && !row1_on)) continue;
#pragma unroll
            for (int wi = 0; wi < 2; ++wi)
#pragma unroll
                for (int pj = 0; pj < 3; ++pj)
#pragma unroll
                    for (int j = 0; j < 4; ++j)
                        so[(wi * 16 + 4 * g + j) * 50 + pj * 16 + r] = acc[row][wi][pj][j];
            asm volatile("s_waitcnt lgkmcnt(0)" ::: "memory");
            __builtin_amdgcn_sched_barrier(0);
            float* op = outb + (size_t)row * WW + (size_t)dy * NKD * (HH * WW);
#pragma unroll
            for (int k = 0; k < 3; ++k) {
                int f = k * 64 + lane;
                if (f < NKD * 8) {
                    int dx = f >> 3, w4l = (f & 7) << 2;   // local w in wave's 32-w slab
                    float4 v;
                    v.x = so[(w4l + 0) * 50 + ((w4l + 0) & 15) + dx];
                    v.y = so[(w4l + 1) * 50 + ((w4l + 1) & 15) + dx];
                    v.z = so[(w4l + 2) * 50 + ((w4l + 2) & 15) + dx];
                    v.w = so[(w4l + 3) * 50 + ((w4l + 3) & 15) + dx];
                    *(float4*)&op[(size_t)dx * (HH * WW) + q * 32 + w4l] = v;
                }
            }
            asm volatile("s_waitcnt lgkmcnt(0)" ::: "memory");  // reads done before row1 rewrites
        }
    }
}

extern "C" void kernel_launch(void* const* d_in, const int* in_sizes, int n_in,
                              void* d_out, int out_size, void* d_ws, size_t ws_size,
                              hipStream_t stream) {
    const float* in = (const float*)d_in[0];
    float* out = (float*)d_out;
    __fp16* img_tgt = (__fp16*)d_ws;

    hipLaunchKernelGGL(pack_tgt, dim3(4 * HPAD), dim3(256), 0, stream, in, img_tgt);
    hipLaunchKernelGGL(corr_mfma, dim3(768), dim3(256), 0, stream, in, img_tgt, out);
}

// Round 17
// 48.838 us; speedup vs baseline: 3.5263x; 1.7767x over previous
//
#include <hip/hip_runtime.h>

#define HH 128
#define WW 128
#define CCH 128
#define NKD 21
#define RAD 10
#define HPAD 148                 // tgt images per b (hp = h+dy, 0..147)
#define ROWH 32                  // halves per row (32c) = 64B
#define CH_HALVES (148 * ROWH)   // 4736 halves per chunk (148 p-rows)
#define CH_BYTES  (CH_HALVES * 2)        // 9472 B
#define IMG_HALVES (4 * CH_HALVES)       // 18944 halves per (b,hp) = 37888 B

typedef _Float16 f16x8 __attribute__((ext_vector_type(8)));
typedef float    f32x4 __attribute__((ext_vector_type(4)));
typedef __fp16   h2f   __attribute__((ext_vector_type(2)));

union PK { uint4 u; h2f h[4]; };

// ------- kernel 1: pack tgt -> f16 image [hp][chunk(32c)][p(148)][32 halves], zero-padded -------
__global__ __launch_bounds__(256)
void pack_tgt(const float* __restrict__ in, __fp16* __restrict__ img) {
    int n = blockIdx.x;                 // 592: b*148 + i (tgt row = i-10)
    int b = n / HPAD, i = n - b * HPAD;
    int tid = threadIdx.x;
    uint4* gi = (uint4*)(img + (size_t)n * IMG_HALVES);   // 2368 uint4 per image
    if (i < RAD || i > 137) {           // h out of range -> all-zero image
        uint4 z = make_uint4(0, 0, 0, 0);
#pragma unroll
        for (int k = 0; k < 9; ++k) gi[k * 256 + tid] = z;
        if (tid < 64) gi[9 * 256 + tid] = z;
        return;
    }
    __shared__ __align__(16) char sraw[4 * CH_BYTES];   // 37888 B
    {   // zero-fill (covers p<10, p>137 pad rows)
        uint4 z = make_uint4(0, 0, 0, 0);
        uint4* sp = (uint4*)sraw;
#pragma unroll
        for (int k = 0; k < 9; ++k) sp[k * 256 + tid] = z;
        if (tid < 64) sp[9 * 256 + tid] = z;
    }
    __syncthreads();
    const float* tg = in + (size_t)(b * 2 + 1) * CCH * HH * WW + (size_t)(i - RAD) * WW;
    int w = tid & 127, half = tid >> 7;
    int p = w + RAD;                    // 10..137
#pragma unroll
    for (int c2 = 0; c2 < 2; ++c2) {
        int cc = half * 2 + c2;         // chunk 0..3 (32 channels each)
#pragma unroll
        for (int g = 0; g < 4; ++g) {   // slot g = halves c_local g*8..g*8+7
            float v[8];
#pragma unroll
            for (int j = 0; j < 8; ++j)
                v[j] = tg[(size_t)(cc * 32 + g * 8 + j) * (HH * WW) + w];
            PK q;
            q.h[0] = __builtin_amdgcn_cvt_pkrtz(v[0], v[1]);
            q.h[1] = __builtin_amdgcn_cvt_pkrtz(v[2], v[3]);
            q.h[2] = __builtin_amdgcn_cvt_pkrtz(v[4], v[5]);
            q.h[3] = __builtin_amdgcn_cvt_pkrtz(v[6], v[7]);
            *(uint4*)(sraw + (size_t)cc * CH_BYTES + p * 64 + g * 16) = q.u;
        }
    }
    __syncthreads();
    const uint4* si = (const uint4*)sraw;
#pragma unroll
    for (int k = 0; k < 9; ++k) gi[k * 256 + tid] = si[k * 256 + tid];
    if (tid < 64) gi[9 * 256 + tid] = si[9 * 256 + tid];
}

// -------- kernel 2: 2-row block, dy-split-2 (grid 512 -> 2 blocks/CU), barrier-free --------
// Block d covers ph_g = d*11 + phl, phl=0..10. row0 dy=ph_g (if <=20), row1 dy=ph_g-1
// (if >=1) — exact disjoint cover of dy 0..20 for both rows.
// B-fragments read directly from packed global image (L2/L3-resident) into a DEPTH-4
// register ring (buf[cc] — compile-time index since 4 chunks/phase); prefetch t+4 gives
// a full phase of lead. No barriers, no LDS staging in the loop.
// MFMA: a (w-rows) FIRST, bfr (p-cols) SECOND -> acc rows=w(4g+j), cols=p(r).
__global__ __launch_bounds__(256, 2)
void corr_mfma(const float* __restrict__ in, const __fp16* __restrict__ img_tgt,
               float* __restrict__ out) {
    int n = blockIdx.x;                 // 512
    int xcd = n & 7, idx = n >> 3;      // idx 0..63
    int u = xcd * 64 + idx;             // d-blocks of a pair adjacent on one XCD
    int d = u & 1;                      // dy-split half
    int hpair = u >> 1;                 // 0..255
    int b = hpair >> 6;                 // 0..3
    int h0 = (hpair & 63) << 1;         // even row base

    // LDS: s_srch (16KB, prologue) overlaid by s_o (25.6KB, wave-private slabs)
    __shared__ __align__(16) char smem[25600];
    __fp16* s_srch = (__fp16*)smem;
    float*  s_o    = (float*)smem;

    int tid = threadIdx.x;
    int q = tid >> 6, lane = tid & 63, r = lane & 15, g = lane >> 4;

    const char* tgbc = (const char*)(img_tgt + (size_t)(b * HPAD) * IMG_HALVES);
    const int hbase = h0 + d * 11;      // hp = hbase + (t>>2), max 126+11+10 = 147

    // ---- pack src rows via 16KB c-half buffer; A-frags to regs ----
    f16x8 a[2][2][4];   // [row][wi][cc-group]
#pragma unroll
    for (int row = 0; row < 2; ++row) {
        const float* src = in + (size_t)(b * 2) * CCH * HH * WW + (size_t)(h0 + row) * WW;
        const float sc = 1.f / 128.f;
        int w = tid & 127, hb = tid >> 7;
#pragma unroll
        for (int chalf = 0; chalf < 2; ++chalf) {
#pragma unroll
            for (int i4 = 0; i4 < 4; ++i4) {
                int t4 = hb * 4 + i4;           // c-block within half, 0..7
                float v[8];
#pragma unroll
                for (int j = 0; j < 8; ++j)
                    v[j] = src[(size_t)(chalf * 64 + t4 * 8 + j) * (HH * WW) + w] * sc;
                PK qq;
                qq.h[0] = __builtin_amdgcn_cvt_pkrtz(v[0], v[1]);
                qq.h[1] = __builtin_amdgcn_cvt_pkrtz(v[2], v[3]);
                qq.h[2] = __builtin_amdgcn_cvt_pkrtz(v[4], v[5]);
                qq.h[3] = __builtin_amdgcn_cvt_pkrtz(v[6], v[7]);
                int slot = t4 ^ (w & 7);
                *(uint4*)&s_srch[w * 64 + slot * 8] = qq.u;
            }
            __syncthreads();
#pragma unroll
            for (int wi = 0; wi < 2; ++wi) {
                int wrow = (2 * q + wi) * 16 + r;
#pragma unroll
                for (int ksl = 0; ksl < 2; ++ksl) {
                    int slot = (ksl * 4 + g) ^ (wrow & 7);
                    a[row][wi][chalf * 2 + ksl] = *(const f16x8*)&s_srch[wrow * 64 + slot * 8];
                }
            }
            asm volatile("s_waitcnt lgkmcnt(0)" ::: "memory");
            __syncthreads();   // frags in regs everywhere before re-pack / s_o overlay
        }
    }

    // ---- static per-thread byte offsets within a chunk (clamped band rows) ----
    // prow>147 clamped to 147: feeds only acc columns p>=148, never stored.
    int off[4];
#pragma unroll
    for (int pi = 0; pi < 4; ++pi) {
        int prow = (2 * q + pi) * 16 + r;
        if (prow > 147) prow = 147;
        off[pi] = prow * 64 + g * 16;
    }

    float* outb = out + (size_t)b * (NKD * NKD) * (HH * WW) + (size_t)h0 * WW;
    float* so = s_o + q * (32 * 50);

    const int tmax = 44;

    // DEPTH-4 register prefetch ring; chunk t lives in buf[t&3] and t&3 == cc (4
    // chunks/phase), so all buf indices are compile-time constants (no scratch).
    uint4 buf[4][4];
#pragma unroll
    for (int c0 = 0; c0 < 4; ++c0) {
        const char* cp = tgbc + ((size_t)hbase * 4 + c0) * CH_BYTES;
#pragma unroll
        for (int pi = 0; pi < 4; ++pi) buf[c0][pi] = *(const uint4*)(cp + off[pi]);
    }

    for (int phl = 0; phl < 11; ++phl) {
        int ph_g = d * 11 + phl;
        int row0_on = (ph_g <= 20);
        int row1_on = (ph_g >= 1);

        f32x4 acc[2][2][3];   // [row][wi][pj]
#pragma unroll
        for (int row = 0; row < 2; ++row)
#pragma unroll
            for (int wi = 0; wi < 2; ++wi)
#pragma unroll
                for (int pj = 0; pj < 3; ++pj)
#pragma unroll
                    for (int j = 0; j < 4; ++j) acc[row][wi][pj][j] = 0.f;

#pragma unroll
        for (int cc = 0; cc < 4; ++cc) {
            int t = phl * 4 + cc;
            f16x8 bfr[4];
#pragma unroll
            for (int pi = 0; pi < 4; ++pi)
                bfr[pi] = __builtin_bit_cast(f16x8, buf[cc][pi]);

            if (t + 4 < tmax) {   // prefetch next phase's cc-chunk into the slot consumed
                const char* cp = tgbc
                    + ((size_t)(hbase + phl + 1) * 4 + cc) * CH_BYTES;
#pragma unroll
                for (int pi = 0; pi < 4; ++pi)
                    buf[cc][pi] = *(const uint4*)(cp + off[pi]);
            }

            if (row0_on) {
#pragma unroll
                for (int wi = 0; wi < 2; ++wi)
#pragma unroll
                    for (int pj = 0; pj < 3; ++pj)
                        acc[0][wi][pj] = __builtin_amdgcn_mfma_f32_16x16x32_f16(
                            a[0][wi][cc], bfr[wi + pj], acc[0][wi][pj], 0, 0, 0);
            }
            if (row1_on) {
#pragma unroll
                for (int wi = 0; wi < 2; ++wi)
#pragma unroll
                    for (int pj = 0; pj < 3; ++pj)
                        acc[1][wi][pj] = __builtin_amdgcn_mfma_f32_16x16x32_f16(
                            a[1][wi][cc], bfr[wi + pj], acc[1][wi][pj], 0, 0, 0);
            }
        }

        // ---- staggered epilogues: row0 dy=ph_g, row1 dy=ph_g-1 (s_o wave-private) ----
#pragma unroll
        for (int row = 0; row < 2; ++row) {
            int dy = ph_g - row;
            if ((row == 0 && !row0_on) || (row == 1 && !row1_on)) continue;
#pragma unroll
            for (int wi = 0; wi < 2; ++wi)
#pragma unroll
                for (int pj = 0; pj < 3; ++pj)
#pragma unroll
                    for (int j = 0; j < 4; ++j)
                        so[(wi * 16 + 4 * g + j) * 50 + pj * 16 + r] = acc[row][wi][pj][j];
            asm volatile("s_waitcnt lgkmcnt(0)" ::: "memory");
            __builtin_amdgcn_sched_barrier(0);
            float* op = outb + (size_t)row * WW + (size_t)dy * NKD * (HH * WW);
#pragma unroll
            for (int k = 0; k < 3; ++k) {
                int f = k * 64 + lane;
                if (f < NKD * 8) {
                    int dx = f >> 3, w4l = (f & 7) << 2;   // local w in wave's 32-w slab
                    float4 v;
                    v.x = so[(w4l + 0) * 50 + ((w4l + 0) & 15) + dx];
                    v.y = so[(w4l + 1) * 50 + ((w4l + 1) & 15) + dx];
                    v.z = so[(w4l + 2) * 50 + ((w4l + 2) & 15) + dx];
                    v.w = so[(w4l + 3) * 50 + ((w4l + 3) & 15) + dx];
                    *(float4*)&op[(size_t)dx * (HH * WW) + q * 32 + w4l] = v;
                }
            }
            asm volatile("s_waitcnt lgkmcnt(0)" ::: "memory");  // reads done before row1 rewrites
        }
    }
}

extern "C" void kernel_launch(void* const* d_in, const int* in_sizes, int n_in,
                              void* d_out, int out_size, void* d_ws, size_t ws_size,
                              hipStream_t stream) {
    const float* in = (const float*)d_in[0];
    float* out = (float*)d_out;
    __fp16* img_tgt = (__fp16*)d_ws;

    hipLaunchKernelGGL(pack_tgt, dim3(4 * HPAD), dim3(256), 0, stream, in, img_tgt);
    hipLaunchKernelGGL(corr_mfma, dim3(512), dim3(256), 0, stream, in, img_tgt, out);
}

// Round 18
// 47.602 us; speedup vs baseline: 3.6180x; 1.0260x over previous
//
#include <hip/hip_runtime.h>

#define HH 128
#define WW 128
#define CCH 128
#define NKD 21
#define RAD 10
#define ROWH 32                  // halves per row (32c) = 64B
#define CH_HALVES (148 * ROWH)   // 4736 halves per chunk (148 p-rows)
#define CH_BYTES  (CH_HALVES * 2)        // 9472 B
#define IMG_HALVES (4 * CH_HALVES)       // 18944 halves per (b,i2) = 37888 B

typedef _Float16 f16x8 __attribute__((ext_vector_type(8)));
typedef float    f32x4 __attribute__((ext_vector_type(4)));
typedef __fp16   h2f   __attribute__((ext_vector_type(2)));

union PK { uint4 u; h2f h[4]; };

// --- kernel 1: pack tgt row i2 -> f16 image [b][i2][chunk(32c)][p(148)][32 halves] ---
// Only in-range rows (hp = i2+10, tgt row = i2); zero-pad rows p<10 / p>137 baked in.
__global__ __launch_bounds__(256)
void pack_tgt(const float* __restrict__ in, __fp16* __restrict__ img) {
    int n = blockIdx.x;                 // 512: b*128 + i2
    int b = n >> 7, i2 = n & 127;
    int tid = threadIdx.x;
    __shared__ __align__(16) char sraw[4 * CH_BYTES];   // 37888 B
    {   // zero-fill (covers p<10, p>137 pad rows)
        uint4 z = make_uint4(0, 0, 0, 0);
        uint4* sp = (uint4*)sraw;
#pragma unroll
        for (int k = 0; k < 9; ++k) sp[k * 256 + tid] = z;
        if (tid < 64) sp[9 * 256 + tid] = z;
    }
    __syncthreads();
    const float* tg = in + (size_t)(b * 2 + 1) * CCH * HH * WW + (size_t)i2 * WW;
    int w = tid & 127, half = tid >> 7;
    int p = w + RAD;                    // 10..137
#pragma unroll
    for (int c2 = 0; c2 < 2; ++c2) {
        int cc = half * 2 + c2;         // chunk 0..3 (32 channels each)
#pragma unroll
        for (int g = 0; g < 4; ++g) {   // slot g = halves c_local g*8..g*8+7
            float v[8];
#pragma unroll
            for (int j = 0; j < 8; ++j)
                v[j] = tg[(size_t)(cc * 32 + g * 8 + j) * (HH * WW) + w];
            PK q;
            q.h[0] = __builtin_amdgcn_cvt_pkrtz(v[0], v[1]);
            q.h[1] = __builtin_amdgcn_cvt_pkrtz(v[2], v[3]);
            q.h[2] = __builtin_amdgcn_cvt_pkrtz(v[4], v[5]);
            q.h[3] = __builtin_amdgcn_cvt_pkrtz(v[6], v[7]);
            *(uint4*)(sraw + (size_t)cc * CH_BYTES + p * 64 + g * 16) = q.u;
        }
    }
    __syncthreads();
    uint4* gi = (uint4*)(img + (size_t)n * IMG_HALVES);   // 2368 uint4
    const uint4* si = (const uint4*)sraw;
#pragma unroll
    for (int k = 0; k < 9; ++k) gi[k * 256 + tid] = si[k * 256 + tid];
    if (tid < 64) gi[9 * 256 + tid] = si[9 * 256 + tid];
}

// -------- kernel 2: 2-row block, dy-split-2, barrier-free, PHASE-ROTATED --------
// Block d covers ph_g = d*11 + phl_a; phl_a cycles (phl0 + it) % 11 with
// phl0 = (-h0) mod 11 so co-resident blocks read the SAME hp images at the same
// time (instantaneous L2 sharing instead of whole-kernel retention).
// hp out of [10,137] -> image is implicitly zero: skip load AND MFMA.
// row0 dy=ph_g (if <=20), row1 dy=ph_g-1 (if >=1) — exact disjoint cover.
// MFMA: a (w-rows) FIRST, bfr (p-cols) SECOND -> acc rows=w(4g+j), cols=p(r).
__global__ __launch_bounds__(256, 2)
void corr_mfma(const float* __restrict__ in, const __fp16* __restrict__ img_tgt,
               float* __restrict__ out) {
    int n = blockIdx.x;                 // 512
    int xcd = n & 7, idx = n >> 3;      // idx 0..63
    int u = xcd * 64 + idx;             // d-blocks of a pair adjacent on one XCD
    int d = u & 1;                      // dy-split half
    int hpair = u >> 1;                 // 0..255
    int b = hpair >> 6;                 // 0..3
    int h0 = (hpair & 63) << 1;         // even row base

    // LDS: s_srch (16KB, prologue) overlaid by s_o (25.6KB, wave-private slabs)
    __shared__ __align__(16) char smem[25600];
    __fp16* s_srch = (__fp16*)smem;
    float*  s_o    = (float*)smem;

    int tid = threadIdx.x;
    int q = tid >> 6, lane = tid & 63, r = lane & 15, g = lane >> 4;

    const char* imgb = (const char*)(img_tgt + (size_t)(b * 128) * IMG_HALVES);
    const int hbase = h0 + d * 11;      // hp = hbase + phl_a
    const int phl0 = (2178 - h0) % 11;  // 2178 = 198*11 keeps it positive

    // ---- pack src rows via 16KB c-half buffer; A-frags to regs ----
    f16x8 a[2][2][4];   // [row][wi][cc-group]
#pragma unroll
    for (int row = 0; row < 2; ++row) {
        const float* src = in + (size_t)(b * 2) * CCH * HH * WW + (size_t)(h0 + row) * WW;
        const float sc = 1.f / 128.f;
        int w = tid & 127, hb = tid >> 7;
#pragma unroll
        for (int chalf = 0; chalf < 2; ++chalf) {
#pragma unroll
            for (int i4 = 0; i4 < 4; ++i4) {
                int t4 = hb * 4 + i4;           // c-block within half, 0..7
                float v[8];
#pragma unroll
                for (int j = 0; j < 8; ++j)
                    v[j] = src[(size_t)(chalf * 64 + t4 * 8 + j) * (HH * WW) + w] * sc;
                PK qq;
                qq.h[0] = __builtin_amdgcn_cvt_pkrtz(v[0], v[1]);
                qq.h[1] = __builtin_amdgcn_cvt_pkrtz(v[2], v[3]);
                qq.h[2] = __builtin_amdgcn_cvt_pkrtz(v[4], v[5]);
                qq.h[3] = __builtin_amdgcn_cvt_pkrtz(v[6], v[7]);
                int slot = t4 ^ (w & 7);
                *(uint4*)&s_srch[w * 64 + slot * 8] = qq.u;
            }
            __syncthreads();
#pragma unroll
            for (int wi = 0; wi < 2; ++wi) {
                int wrow = (2 * q + wi) * 16 + r;
#pragma unroll
                for (int ksl = 0; ksl < 2; ++ksl) {
                    int slot = (ksl * 4 + g) ^ (wrow & 7);
                    a[row][wi][chalf * 2 + ksl] = *(const f16x8*)&s_srch[wrow * 64 + slot * 8];
                }
            }
            asm volatile("s_waitcnt lgkmcnt(0)" ::: "memory");
            __syncthreads();   // frags in regs everywhere before re-pack / s_o overlay
        }
    }

    // ---- static per-thread byte offsets within a chunk (clamped band rows) ----
    // prow>147 clamped to 147: feeds only acc columns p>=148, never stored.
    int off[4];
#pragma unroll
    for (int pi = 0; pi < 4; ++pi) {
        int prow = (2 * q + pi) * 16 + r;
        if (prow > 147) prow = 147;
        off[pi] = prow * 64 + g * 16;
    }

    float* outb = out + (size_t)b * (NKD * NKD) * (HH * WW) + (size_t)h0 * WW;
    float* so = s_o + q * (32 * 50);

    // chunk base pointer for phase phl_a (hp = hbase+phl_a), or null if zero-image
    auto chunk_base = [&](int phl_a) -> const char* {
        int hp = hbase + phl_a;
        if (hp < RAD || hp > 137) return nullptr;
        return imgb + (size_t)(hp - RAD) * (IMG_HALVES * 2);
    };

    // DEPTH-4 register ring; phase it holds its 4 chunks in buf[0..3] (slot = cc).
    uint4 buf[4][4];
    {
        const char* cb = chunk_base(phl0);
        if (cb) {
#pragma unroll
            for (int c0 = 0; c0 < 4; ++c0)
#pragma unroll
                for (int pi = 0; pi < 4; ++pi)
                    buf[c0][pi] = *(const uint4*)(cb + c0 * CH_BYTES + off[pi]);
        }
    }

    for (int it = 0; it < 11; ++it) {
        int phl_a = phl0 + it; if (phl_a >= 11) phl_a -= 11;
        int ph_g = d * 11 + phl_a;
        int row0_on = (ph_g <= 20);
        int row1_on = (ph_g >= 1);
        bool cur_ok = (chunk_base(phl_a) != nullptr);

        const char* nxt = nullptr;
        if (it + 1 < 11) {
            int phl_n = phl_a + 1; if (phl_n >= 11) phl_n -= 11;
            nxt = chunk_base(phl_n);
        }

        f32x4 acc[2][2][3];   // [row][wi][pj]
#pragma unroll
        for (int row = 0; row < 2; ++row)
#pragma unroll
            for (int wi = 0; wi < 2; ++wi)
#pragma unroll
                for (int pj = 0; pj < 3; ++pj)
#pragma unroll
                    for (int j = 0; j < 4; ++j) acc[row][wi][pj][j] = 0.f;

#pragma unroll
        for (int cc = 0; cc < 4; ++cc) {
            f16x8 bfr[4];
#pragma unroll
            for (int pi = 0; pi < 4; ++pi)
                bfr[pi] = __builtin_bit_cast(f16x8, buf[cc][pi]);

            if (nxt) {   // prefetch next phase's cc-chunk into the slot just consumed
#pragma unroll
                for (int pi = 0; pi < 4; ++pi)
                    buf[cc][pi] = *(const uint4*)(nxt + cc * CH_BYTES + off[pi]);
            }

            if (cur_ok && row0_on) {
#pragma unroll
                for (int wi = 0; wi < 2; ++wi)
#pragma unroll
                    for (int pj = 0; pj < 3; ++pj)
                        acc[0][wi][pj] = __builtin_amdgcn_mfma_f32_16x16x32_f16(
                            a[0][wi][cc], bfr[wi + pj], acc[0][wi][pj], 0, 0, 0);
            }
            if (cur_ok && row1_on) {
#pragma unroll
                for (int wi = 0; wi < 2; ++wi)
#pragma unroll
                    for (int pj = 0; pj < 3; ++pj)
                        acc[1][wi][pj] = __builtin_amdgcn_mfma_f32_16x16x32_f16(
                            a[1][wi][cc], bfr[wi + pj], acc[1][wi][pj], 0, 0, 0);
            }
        }

        // ---- staggered epilogues: row0 dy=ph_g, row1 dy=ph_g-1 (s_o wave-private) ----
        // Runs even when cur_ok==false (acc==0 -> output zeros, matching reference pad).
#pragma unroll
        for (int row = 0; row < 2; ++row) {
            int dy = ph_g - row;
            if ((row == 0 && !row0_on) || (row == 1 && !row1_on)) continue;
#pragma unroll
            for (int wi = 0; wi < 2; ++wi)
#pragma unroll
                for (int pj = 0; pj < 3; ++pj)
#pragma unroll
                    for (int j = 0; j < 4; ++j)
                        so[(wi * 16 + 4 * g + j) * 50 + pj * 16 + r] = acc[row][wi][pj][j];
            asm volatile("s_waitcnt lgkmcnt(0)" ::: "memory");
            __builtin_amdgcn_sched_barrier(0);
            float* op = outb + (size_t)row * WW + (size_t)dy * NKD * (HH * WW);
#pragma unroll
            for (int k = 0; k < 3; ++k) {
                int f = k * 64 + lane;
                if (f < NKD * 8) {
                    int dx = f >> 3, w4l = (f & 7) << 2;   // local w in wave's 32-w slab
                    float4 v;
                    v.x = so[(w4l + 0) * 50 + ((w4l + 0) & 15) + dx];
                    v.y = so[(w4l + 1) * 50 + ((w4l + 1) & 15) + dx];
                    v.z = so[(w4l + 2) * 50 + ((w4l + 2) & 15) + dx];
                    v.w = so[(w4l + 3) * 50 + ((w4l + 3) & 15) + dx];
                    *(float4*)&op[(size_t)dx * (HH * WW) + q * 32 + w4l] = v;
                }
            }
            asm volatile("s_waitcnt lgkmcnt(0)" ::: "memory");  // reads done before row1 rewrites
        }
    }
}

extern "C" void kernel_launch(void* const* d_in, const int* in_sizes, int n_in,
                              void* d_out, int out_size, void* d_ws, size_t ws_size,
                              hipStream_t stream) {
    const float* in = (const float*)d_in[0];
    float* out = (float*)d_out;
    __fp16* img_tgt = (__fp16*)d_ws;

    hipLaunchKernelGGL(pack_tgt, dim3(512), dim3(256), 0, stream, in, img_tgt);
    hipLaunchKernelGGL(corr_mfma, dim3(512), dim3(256), 0, stream, in, img_tgt, out);
}

// Round 19
// 47.483 us; speedup vs baseline: 3.6270x; 1.0025x over previous
//
#include <hip/hip_runtime.h>

#define HH 128
#define WW 128
#define CCH 128
#define NKD 21
#define RAD 10
#define ROWH 32                  // halves per row (32c) = 64B
#define CH_HALVES (148 * ROWH)   // 4736 halves per chunk (148 p-rows)
#define CH_BYTES  (CH_HALVES * 2)        // 9472 B
#define IMG_HALVES (4 * CH_HALVES)       // 18944 halves per (b,i2) = 37888 B
#define SO_STRIDE 66             // s_o row stride (floats): odd+1 diagonal -> conflict-free
#define SO_WAVE   2112           // floats per wave slab (32*66, 16B-aligned)

typedef _Float16 f16x8 __attribute__((ext_vector_type(8)));
typedef float    f32x4 __attribute__((ext_vector_type(4)));
typedef __fp16   h2f   __attribute__((ext_vector_type(2)));

union PK { uint4 u; h2f h[4]; };

// --- kernel 1: pack tgt row i2 -> f16 image [b][i2][chunk(32c)][p(148)][32 halves] ---
__global__ __launch_bounds__(256)
void pack_tgt(const float* __restrict__ in, __fp16* __restrict__ img) {
    int n = blockIdx.x;                 // 512: b*128 + i2
    int b = n >> 7, i2 = n & 127;
    int tid = threadIdx.x;
    __shared__ __align__(16) char sraw[4 * CH_BYTES];   // 37888 B
    {   // zero-fill (covers p<10, p>137 pad rows)
        uint4 z = make_uint4(0, 0, 0, 0);
        uint4* sp = (uint4*)sraw;
#pragma unroll
        for (int k = 0; k < 9; ++k) sp[k * 256 + tid] = z;
        if (tid < 64) sp[9 * 256 + tid] = z;
    }
    __syncthreads();
    const float* tg = in + (size_t)(b * 2 + 1) * CCH * HH * WW + (size_t)i2 * WW;
    int w = tid & 127, half = tid >> 7;
    int p = w + RAD;                    // 10..137
#pragma unroll
    for (int c2 = 0; c2 < 2; ++c2) {
        int cc = half * 2 + c2;         // chunk 0..3 (32 channels each)
#pragma unroll
        for (int g = 0; g < 4; ++g) {   // slot g = halves c_local g*8..g*8+7
            float v[8];
#pragma unroll
            for (int j = 0; j < 8; ++j)
                v[j] = tg[(size_t)(cc * 32 + g * 8 + j) * (HH * WW) + w];
            PK q;
            q.h[0] = __builtin_amdgcn_cvt_pkrtz(v[0], v[1]);
            q.h[1] = __builtin_amdgcn_cvt_pkrtz(v[2], v[3]);
            q.h[2] = __builtin_amdgcn_cvt_pkrtz(v[4], v[5]);
            q.h[3] = __builtin_amdgcn_cvt_pkrtz(v[6], v[7]);
            *(uint4*)(sraw + (size_t)cc * CH_BYTES + p * 64 + g * 16) = q.u;
        }
    }
    __syncthreads();
    uint4* gi = (uint4*)(img + (size_t)n * IMG_HALVES);   // 2368 uint4
    const uint4* si = (const uint4*)sraw;
#pragma unroll
    for (int k = 0; k < 9; ++k) gi[k * 256 + tid] = si[k * 256 + tid];
    if (tid < 64) gi[9 * 256 + tid] = si[9 * 256 + tid];
}

// -------- kernel 2: 2-row block, dy-split-2, barrier-free, phase-rotated --------
// s_o layout: so[w_local][p_local] stride 66 — writes (12g+r banks, ~2-way) and the
// diagonal reads so[67*(w+j)+dx] (distinct banks mod exact 2-way pairs) conflict-free.
// MFMA: a (w-rows) FIRST, bfr (p-cols) SECOND -> acc rows=w(4g+j), cols=p(r).
__global__ __launch_bounds__(256, 2)
void corr_mfma(const float* __restrict__ in, const __fp16* __restrict__ img_tgt,
               float* __restrict__ out) {
    int n = blockIdx.x;                 // 512
    int xcd = n & 7, idx = n >> 3;      // idx 0..63
    int u = xcd * 64 + idx;             // d-blocks of a pair adjacent on one XCD
    int d = u & 1;                      // dy-split half
    int hpair = u >> 1;                 // 0..255
    int b = hpair >> 6;                 // 0..3
    int h0 = (hpair & 63) << 1;         // even row base

    // LDS: s_srch (16KB, prologue) overlaid by s_o (33792B, wave-private slabs)
    __shared__ __align__(16) char smem[4 * SO_WAVE * 4];
    __fp16* s_srch = (__fp16*)smem;
    float*  s_o    = (float*)smem;

    int tid = threadIdx.x;
    int q = tid >> 6, lane = tid & 63, r = lane & 15, g = lane >> 4;

    const char* imgb = (const char*)(img_tgt + (size_t)(b * 128) * IMG_HALVES);
    const int hbase = h0 + d * 11;      // hp = hbase + phl_a
    const int phl0 = (2178 - h0) % 11;  // phase rotation for instantaneous L2 sharing

    // ---- pack src rows via 16KB c-half buffer; A-frags to regs ----
    f16x8 a[2][2][4];   // [row][wi][cc-group]
#pragma unroll
    for (int row = 0; row < 2; ++row) {
        const float* src = in + (size_t)(b * 2) * CCH * HH * WW + (size_t)(h0 + row) * WW;
        const float sc = 1.f / 128.f;
        int w = tid & 127, hb = tid >> 7;
#pragma unroll
        for (int chalf = 0; chalf < 2; ++chalf) {
#pragma unroll
            for (int i4 = 0; i4 < 4; ++i4) {
                int t4 = hb * 4 + i4;           // c-block within half, 0..7
                float v[8];
#pragma unroll
                for (int j = 0; j < 8; ++j)
                    v[j] = src[(size_t)(chalf * 64 + t4 * 8 + j) * (HH * WW) + w] * sc;
                PK qq;
                qq.h[0] = __builtin_amdgcn_cvt_pkrtz(v[0], v[1]);
                qq.h[1] = __builtin_amdgcn_cvt_pkrtz(v[2], v[3]);
                qq.h[2] = __builtin_amdgcn_cvt_pkrtz(v[4], v[5]);
                qq.h[3] = __builtin_amdgcn_cvt_pkrtz(v[6], v[7]);
                int slot = t4 ^ (w & 7);
                *(uint4*)&s_srch[w * 64 + slot * 8] = qq.u;
            }
            __syncthreads();
#pragma unroll
            for (int wi = 0; wi < 2; ++wi) {
                int wrow = (2 * q + wi) * 16 + r;
#pragma unroll
                for (int ksl = 0; ksl < 2; ++ksl) {
                    int slot = (ksl * 4 + g) ^ (wrow & 7);
                    a[row][wi][chalf * 2 + ksl] = *(const f16x8*)&s_srch[wrow * 64 + slot * 8];
                }
            }
            asm volatile("s_waitcnt lgkmcnt(0)" ::: "memory");
            __syncthreads();   // frags in regs everywhere before re-pack / s_o overlay
        }
    }

    // ---- static per-thread byte offsets within a chunk (clamped band rows) ----
    int off[4];
#pragma unroll
    for (int pi = 0; pi < 4; ++pi) {
        int prow = (2 * q + pi) * 16 + r;
        if (prow > 147) prow = 147;
        off[pi] = prow * 64 + g * 16;
    }

    float* outb = out + (size_t)b * (NKD * NKD) * (HH * WW) + (size_t)h0 * WW;
    float* so = s_o + q * SO_WAVE;

    auto chunk_base = [&](int phl_a) -> const char* {
        int hp = hbase + phl_a;
        if (hp < RAD || hp > 137) return nullptr;
        return imgb + (size_t)(hp - RAD) * (IMG_HALVES * 2);
    };

    // DEPTH-4 register ring; phase holds its 4 chunks in buf[0..3] (slot = cc).
    uint4 buf[4][4];
    {
        const char* cb = chunk_base(phl0);
        if (cb) {
#pragma unroll
            for (int c0 = 0; c0 < 4; ++c0)
#pragma unroll
                for (int pi = 0; pi < 4; ++pi)
                    buf[c0][pi] = *(const uint4*)(cb + c0 * CH_BYTES + off[pi]);
        }
    }

    for (int it = 0; it < 11; ++it) {
        int phl_a = phl0 + it; if (phl_a >= 11) phl_a -= 11;
        int ph_g = d * 11 + phl_a;
        int row0_on = (ph_g <= 20);
        int row1_on = (ph_g >= 1);
        bool cur_ok = (chunk_base(phl_a) != nullptr);

        const char* nxt = nullptr;
        if (it + 1 < 11) {
            int phl_n = phl_a + 1; if (phl_n >= 11) phl_n -= 11;
            nxt = chunk_base(phl_n);
        }

        f32x4 acc[2][2][3];   // [row][wi][pj]
#pragma unroll
        for (int row = 0; row < 2; ++row)
#pragma unroll
            for (int wi = 0; wi < 2; ++wi)
#pragma unroll
                for (int pj = 0; pj < 3; ++pj)
#pragma unroll
                    for (int j = 0; j < 4; ++j) acc[row][wi][pj][j] = 0.f;

#pragma unroll
        for (int cc = 0; cc < 4; ++cc) {
            f16x8 bfr[4];
#pragma unroll
            for (int pi = 0; pi < 4; ++pi)
                bfr[pi] = __builtin_bit_cast(f16x8, buf[cc][pi]);

            if (nxt) {   // prefetch next phase's cc-chunk into the slot just consumed
#pragma unroll
                for (int pi = 0; pi < 4; ++pi)
                    buf[cc][pi] = *(const uint4*)(nxt + cc * CH_BYTES + off[pi]);
            }

            if (cur_ok && row0_on) {
#pragma unroll
                for (int wi = 0; wi < 2; ++wi)
#pragma unroll
                    for (int pj = 0; pj < 3; ++pj)
                        acc[0][wi][pj] = __builtin_amdgcn_mfma_f32_16x16x32_f16(
                            a[0][wi][cc], bfr[wi + pj], acc[0][wi][pj], 0, 0, 0);
            }
            if (cur_ok && row1_on) {
#pragma unroll
                for (int wi = 0; wi < 2; ++wi)
#pragma unroll
                    for (int pj = 0; pj < 3; ++pj)
                        acc[1][wi][pj] = __builtin_amdgcn_mfma_f32_16x16x32_f16(
                            a[1][wi][cc], bfr[wi + pj], acc[1][wi][pj], 0, 0, 0);
            }
        }

        // ---- staggered epilogues: row0 dy=ph_g, row1 dy=ph_g-1 (s_o wave-private) ----
#pragma unroll
        for (int row = 0; row < 2; ++row) {
            int dy = ph_g - row;
            if ((row == 0 && !row0_on) || (row == 1 && !row1_on)) continue;
            // write: so[w_local*66 + p_local], p_local = (wi+pj)*16 + r
#pragma unroll
            for (int wi = 0; wi < 2; ++wi)
#pragma unroll
                for (int pj = 0; pj < 3; ++pj)
#pragma unroll
                    for (int j = 0; j < 4; ++j)
                        so[(wi * 16 + 4 * g + j) * SO_STRIDE + (wi + pj) * 16 + r]
                            = acc[row][wi][pj][j];
            asm volatile("s_waitcnt lgkmcnt(0)" ::: "memory");
            __builtin_amdgcn_sched_barrier(0);
            float* op = outb + (size_t)row * WW + (size_t)dy * NKD * (HH * WW);
#pragma unroll
            for (int k = 0; k < 3; ++k) {
                int f = k * 64 + lane;
                if (f < NKD * 8) {
                    int dx = f >> 3, w4l = (f & 7) << 2;   // local w in wave's 32-w slab
                    float4 v;   // read: so[67*(w_local+j) + dx] — diagonal, conflict-free
                    v.x = so[67 * (w4l + 0) + dx];
                    v.y = so[67 * (w4l + 1) + dx];
                    v.z = so[67 * (w4l + 2) + dx];
                    v.w = so[67 * (w4l + 3) + dx];
                    *(float4*)&op[(size_t)dx * (HH * WW) + q * 32 + w4l] = v;
                }
            }
            asm volatile("s_waitcnt lgkmcnt(0)" ::: "memory");  // reads done before row1 rewrites
        }
    }
}

extern "C" void kernel_launch(void* const* d_in, const int* in_sizes, int n_in,
                              void* d_out, int out_size, void* d_ws, size_t ws_size,
                              hipStream_t stream) {
    const float* in = (const float*)d_in[0];
    float* out = (float*)d_out;
    __fp16* img_tgt = (__fp16*)d_ws;

    hipLaunchKernelGGL(pack_tgt, dim3(512), dim3(256), 0, stream, in, img_tgt);
    hipLaunchKernelGGL(corr_mfma, dim3(512), dim3(256), 0, stream, in, img_tgt, out);
}